// Round 4
// baseline (184.113 us; speedup 1.0000x reference)
//
#include <hip/hip_runtime.h>

typedef __bf16 bf16;
typedef __bf16 bf16x4 __attribute__((ext_vector_type(4)));
typedef __bf16 bf16x8 __attribute__((ext_vector_type(8)));
typedef float f32x4 __attribute__((ext_vector_type(4)));

#define S_LEN 2048
#define D_DIM 1024
#define N_HEAD 16
#define HEAD_DIM 64
#define M_TOK 4096
#define BH 32

#define EXP2F(x) __builtin_amdgcn_exp2f(x)
// 1/sqrt(64) * log2(e)
#define Q_SCALE 0.18033688f
// defer-max threshold (log2 domain): skip m/acc rescale while max growth <= 8
#define RESCALE_THR 8.0f

// LDS bank swizzle: conflict-free for our b64/b128 access patterns (stride 64, no pad)
#define SW(r, c) ((c) ^ (((r) & 3) << 4))
// K-row bit permutation sigma: bit2->bit4, bit4->bit3, bit3->bit2.
// Storing K row kpos at LDS row sigma(kpos) makes the QK^T output's P matrix
// lane-local for the PV MFMA B-operand (pf[ks] = {p[2ks][0..3], p[2ks+1][0..3]}),
// eliminating the Ps LDS round-trip entirely. sigma preserves (r&3) so
// SW(sigma(r),c) == SW(r,c).
#define SIG(r) (((r) & 0x23) | (((r) & 0x04) << 2) | (((r) & 0x18) >> 1))

typedef __attribute__((address_space(3))) void lds_void;
typedef const __attribute__((address_space(1))) void gbl_void;

__device__ __forceinline__ void gl_lds16(const bf16* g, bf16* l) {
  __builtin_amdgcn_global_load_lds((gbl_void*)g, (lds_void*)l, 16, 0, 0);
}

// ---------------- cast fp32 -> bf16 ----------------
__global__ __launch_bounds__(256) void k_cast(const float* __restrict__ x,
                                              bf16* __restrict__ o, int n) {
  int i = (blockIdx.x * 256 + threadIdx.x) * 4;
  if (i >= n) return;
  float4 v = *(const float4*)(x + i);
  bf16x4 w;
  w[0] = (bf16)v.x; w[1] = (bf16)v.y; w[2] = (bf16)v.z; w[3] = (bf16)v.w;
  *(bf16x4*)(o + i) = w;
}

// ---------------- transpose+cast: W[K][N] fp32 -> Wt[N][K] bf16 ----------------
__global__ __launch_bounds__(256) void k_transpose(const float* __restrict__ W,
                                                   bf16* __restrict__ Wt,
                                                   int K, int N) {
  __shared__ float tile[32][33];
  int nb = blockIdx.x, kb = blockIdx.y;
  int t = threadIdx.x;
  int r = t >> 3, c4 = (t & 7) * 4;
  float4 v = *(const float4*)&W[(kb * 32 + r) * N + nb * 32 + c4];
  tile[r][c4 + 0] = v.x; tile[r][c4 + 1] = v.y;
  tile[r][c4 + 2] = v.z; tile[r][c4 + 3] = v.w;
  __syncthreads();
  bf16x4 o;
  #pragma unroll
  for (int i = 0; i < 4; i++) o[i] = (bf16)tile[c4 + i][r];
  *(bf16x4*)&Wt[(nb * 32 + r) * K + kb * 32 + c4] = o;
}

// ---------------- GEMM1: qkv = x @ W_attn + b_attn ----------------
__global__ __launch_bounds__(256, 2)
void k_gemm_qkv(const bf16* __restrict__ A, const bf16* __restrict__ Bt,
                const float* __restrict__ bias,
                bf16* __restrict__ qk, bf16* __restrict__ vT) {
  __shared__ bf16 As[128 * 32];
  __shared__ bf16 Bs[128 * 32];
  const int K = 1024;
  int bn = blockIdx.x, bm = blockIdx.y;
  int t = threadIdx.x;
  int wave = t >> 6, lane = t & 63, c = lane & 15, quad = lane >> 4;
  int wm = wave & 1, wn = wave >> 1;
  int ldrow = lane >> 2, ldcol = (lane & 3) * 8;

  const bf16* Ag = A + (size_t)(bm * 128) * K;
  const bf16* Bg = Bt + (size_t)(bn * 128) * K;

  f32x4 acc[4][4] = {};

  for (int k0 = 0; k0 < K; k0 += 32) {
    __syncthreads();
    #pragma unroll
    for (int q = 0; q < 2; q++) {
      int r0 = (wave * 2 + q) * 16;
      gl_lds16(&Ag[(size_t)(r0 + ldrow) * K + k0 + ldcol], &As[r0 * 32]);
      gl_lds16(&Bg[(size_t)(r0 + ldrow) * K + k0 + ldcol], &Bs[r0 * 32]);
    }
    __syncthreads();
    bf16x8 af[4];
    #pragma unroll
    for (int mt = 0; mt < 4; mt++)
      af[mt] = *(const bf16x8*)&As[(wm * 64 + mt * 16 + c) * 32 + quad * 8];
    #pragma unroll
    for (int nt = 0; nt < 4; nt++) {
      bf16x8 bfr = *(const bf16x8*)&Bs[(wn * 64 + nt * 16 + c) * 32 + quad * 8];
      #pragma unroll
      for (int mt = 0; mt < 4; mt++)
        acc[mt][nt] = __builtin_amdgcn_mfma_f32_16x16x32_bf16(af[mt], bfr, acc[mt][nt], 0, 0, 0);
    }
  }

  #pragma unroll
  for (int nt = 0; nt < 4; nt++) {
    int n = bn * 128 + wn * 64 + nt * 16 + c;
    int which = n >> 10, nl = n & 1023;
    int h = nl >> 6, hd = nl & 63;
    float bv = bias[n];
    #pragma unroll
    for (int mt = 0; mt < 4; mt++) {
      int m0 = bm * 128 + wm * 64 + mt * 16 + quad * 4;
      int b = m0 >> 11, s0 = m0 & 2047;
      int bh = b * N_HEAD + h;
      if (which == 2) {
        bf16x4 o;
        #pragma unroll
        for (int r = 0; r < 4; r++) o[r] = (bf16)(acc[mt][nt][r] + bv);
        *(bf16x4*)&vT[((size_t)bh * HEAD_DIM + hd) * S_LEN + s0] = o;
      } else if (which == 0) {
        #pragma unroll
        for (int r = 0; r < 4; r++)
          qk[(bh * S_LEN + s0 + r) * HEAD_DIM + hd] = (bf16)((acc[mt][nt][r] + bv) * Q_SCALE);
      } else {
        #pragma unroll
        for (int r = 0; r < 4; r++)
          qk[BH * S_LEN * HEAD_DIM + (bh * S_LEN + s0 + r) * HEAD_DIM + hd] = (bf16)(acc[mt][nt][r] + bv);
      }
    }
  }
}

// ---------------- flash attention (causal), paired q-tiles, 512 threads ----------------
// grid 512. Block->pair map is complementary: i<256 -> p=i>>5 (0..7);
// i>=256 -> p=15-((i-256)>>5) (15..8). Under round-robin dispatch, blocks i and
// i+256 co-reside on a CU: loop lengths (32-p) + (17+p) = 49 = constant CU
// work, and both share bh (K/V L2 reuse). Waves 0-3 own q-tile p, waves 4-7
// own q-tile 31-p; one shared K/V double-buffer (32KB LDS).
// 2-deep pipeline (T15): QK(kb+1) runs in parallel with softmax(kb)+PV(kb) -
// the serial chain per iter is softmax->PV only. End of iter kb writes
// Ks[kb+2] (buffer kb&1: its last reader was QK(kb) in iter kb-1) and
// Vs[kb+1] (buffer (kb+1)&1: last reader PV(kb-1)); visibility via next iter's
// top barrier. P stays in registers via the SIG row permutation of K.
// Defer-max (T13): skip m/acc rescale while max growth <= 2^8.
__global__ __launch_bounds__(512, 4)
void k_attn(const bf16* __restrict__ qk, const bf16* __restrict__ vT,
            bf16* __restrict__ y) {
  __shared__ bf16 Ks[2][64][64];   // [buf][sig(kpos)][d]  (swizzled cols)
  __shared__ bf16 Vs[2][64][64];   // [buf][d][kpos]
  int bx = blockIdx.x;
  int bh, p;
  if (bx < 256) { bh = bx & 31; p = bx >> 5; }
  else          { int j = bx - 256; bh = j & 31; p = 15 - (j >> 5); }
  int t = threadIdx.x, w = t >> 6, lane = t & 63, c = lane & 15, quad = lane >> 4;
  int strip = w >> 2, wr = w & 3;
  int myTile = strip ? (31 - p) : p;
  const bf16* Qg = qk + (size_t)bh * (S_LEN * HEAD_DIM);
  const bf16* Kg = qk + (size_t)(BH + bh) * (S_LEN * HEAD_DIM);
  const bf16* Vg = vT + (size_t)bh * (HEAD_DIM * S_LEN);
  int b = bh >> 4, h = bh & 15;
  int srow = t >> 3, scol = (t & 7) * 8;   // 512 thr = 64 rows x 8 x 16B
  int swcol = SW(srow, scol);
  int sigr = SIG(srow);

  const int nkb = 32 - p;                    // loop length (strip 1 runs all)
  const int myLast = strip ? (31 - p) : p;   // diagonal kb for this strip
  const int dthr = wr * 16 + c;              // q-row within tile (diag mask)

  bf16x8 qf[2];
  f32x4 acc[4] = {};
  float mM = -1e30f, lL = 0.f;
  {
    int qr = myTile * 64 + wr * 16 + c;
    qf[0] = *(const bf16x8*)&Qg[qr * HEAD_DIM + quad * 8];
    qf[1] = *(const bf16x8*)&Qg[qr * HEAD_DIM + 32 + quad * 8];
  }

  // ---- prologue: stage kb=0, then QK(0); pre-write Ks[1] ----
  {
    bf16x8 k0 = *(const bf16x8*)&Kg[srow * HEAD_DIM + scol];
    bf16x8 v0 = *(const bf16x8*)&Vg[(size_t)srow * S_LEN + scol];
    *(bf16x8*)&Ks[0][sigr][swcol] = k0;
    *(bf16x8*)&Vs[0][srow][swcol] = v0;
  }
  bf16x8 kr = *(const bf16x8*)&Kg[(64 + srow) * HEAD_DIM + scol];  // K(1)
  bf16x8 vr;
  __syncthreads();   // Ks[0], Vs[0] visible

  // scC = scores(kb=0): lane (c,quad) reg (kt,r) holds score for
  // kpos = (kt>>1)*32 + quad*8 + (kt&1)*4 + r, q-col = c.
  f32x4 scC[4], scN[4];
  __builtin_amdgcn_s_setprio(1);
  #pragma unroll
  for (int kt = 0; kt < 4; kt++) {
    int krr = kt * 16 + c;
    bf16x8 kf0 = *(const bf16x8*)&Ks[0][krr][SW(krr, quad * 8)];
    bf16x8 kf1 = *(const bf16x8*)&Ks[0][krr][SW(krr, 32 + quad * 8)];
    f32x4 z = {};
    z = __builtin_amdgcn_mfma_f32_16x16x32_bf16(kf0, qf[0], z, 0, 0, 0);
    z = __builtin_amdgcn_mfma_f32_16x16x32_bf16(kf1, qf[1], z, 0, 0, 0);
    scC[kt] = z;
  }
  __builtin_amdgcn_s_setprio(0);
  // write Ks[1]; visible at top-of-iter-0 barrier (nkb >= 17 always)
  *(bf16x8*)&Ks[1][sigr][swcol] = kr;

  for (int kb = 0; kb < nkb; kb++) {
    __syncthreads();   // Ks[kb+1] (written iter kb-1 / prologue), Vs[kb] visible
    int cur = kb & 1;
    bool haveK2 = (kb + 2 < nkb);
    bool haveV1 = (kb + 1 < nkb);
    if (haveK2) kr = *(const bf16x8*)&Kg[((kb + 2) * 64 + srow) * HEAD_DIM + scol];
    if (haveV1) vr = *(const bf16x8*)&Vg[(size_t)srow * S_LEN + (kb + 1) * 64 + scol];

    // ---- QK(kb+1) from Ks[cur^1] (parallel with softmax(kb) below) ----
    if (kb + 1 <= myLast) {
      __builtin_amdgcn_s_setprio(1);
      #pragma unroll
      for (int kt = 0; kt < 4; kt++) {
        int krr = kt * 16 + c;
        bf16x8 kf0 = *(const bf16x8*)&Ks[cur ^ 1][krr][SW(krr, quad * 8)];
        bf16x8 kf1 = *(const bf16x8*)&Ks[cur ^ 1][krr][SW(krr, 32 + quad * 8)];
        f32x4 z = {};
        z = __builtin_amdgcn_mfma_f32_16x16x32_bf16(kf0, qf[0], z, 0, 0, 0);
        z = __builtin_amdgcn_mfma_f32_16x16x32_bf16(kf1, qf[1], z, 0, 0, 0);
        scN[kt] = z;
      }
      __builtin_amdgcn_s_setprio(0);
    }

    if (kb <= myLast) {
      // diagonal mask at consumption time
      if (kb == myLast) {
        #pragma unroll
        for (int kt = 0; kt < 4; kt++) {
          int kbase = (kt >> 1) * 32 + quad * 8 + (kt & 1) * 4;
          #pragma unroll
          for (int r = 0; r < 4; r++)
            if (kbase + r > dthr) scC[kt][r] = -1e30f;
        }
      }

      // online softmax (lane's q-row = c); tree reductions; defer-max
      bf16x8 pf[2];
      {
        float tm[4];
        #pragma unroll
        for (int kt = 0; kt < 4; kt++)
          tm[kt] = fmaxf(fmaxf(scC[kt][0], scC[kt][1]), fmaxf(scC[kt][2], scC[kt][3]));
        float mx = fmaxf(fmaxf(tm[0], tm[1]), fmaxf(tm[2], tm[3]));
        mx = fmaxf(mx, __shfl_xor(mx, 16));
        mx = fmaxf(mx, __shfl_xor(mx, 32));
        if (!__all(mx <= mM + RESCALE_THR)) {
          float mnew = fmaxf(mM, mx);
          float alpha = EXP2F(mM - mnew);
          lL *= alpha;
          #pragma unroll
          for (int dt = 0; dt < 4; dt++)
            #pragma unroll
            for (int r = 0; r < 4; r++) acc[dt][r] *= alpha;
          mM = mnew;
        }
        float pv[16];
        #pragma unroll
        for (int kt = 0; kt < 4; kt++)
          #pragma unroll
          for (int r = 0; r < 4; r++) {
            float e = EXP2F(scC[kt][r] - mM);
            pv[kt * 4 + r] = e;
            pf[kt >> 1][(kt & 1) * 4 + r] = (bf16)e;
          }
        float s0 = (pv[0] + pv[1]) + (pv[2] + pv[3]);
        float s1 = (pv[4] + pv[5]) + (pv[6] + pv[7]);
        float s2 = (pv[8] + pv[9]) + (pv[10] + pv[11]);
        float s3 = (pv[12] + pv[13]) + (pv[14] + pv[15]);
        float sum = (s0 + s1) + (s2 + s3);
        sum += __shfl_xor(sum, 16);
        sum += __shfl_xor(sum, 32);
        lL += sum;
      }

      // O^T += V^T P^T  (pf kpos order matches Vs natural column order)
      __builtin_amdgcn_s_setprio(1);
      #pragma unroll
      for (int ks = 0; ks < 2; ks++) {
        #pragma unroll
        for (int dt = 0; dt < 4; dt++) {
          int vrow = dt * 16 + c;
          bf16x8 vf = *(const bf16x8*)&Vs[cur][vrow][SW(vrow, ks * 32 + quad * 8)];
          acc[dt] = __builtin_amdgcn_mfma_f32_16x16x32_bf16(vf, pf[ks], acc[dt], 0, 0, 0);
        }
      }
      __builtin_amdgcn_s_setprio(0);
    }

    // stage: Ks[kb+2] -> buffer cur (last read by QK(kb) in iter kb-1);
    //        Vs[kb+1] -> buffer cur^1 (last read by PV(kb-1) in iter kb-1)
    if (haveK2) *(bf16x8*)&Ks[cur][sigr][swcol] = kr;
    if (haveV1) *(bf16x8*)&Vs[cur ^ 1][srow][swcol] = vr;

    // rotate score buffers (static indexing; 16 v_mov, off critical path)
    #pragma unroll
    for (int kt = 0; kt < 4; kt++) scC[kt] = scN[kt];
  }

  {
    int q = myTile * 64 + wr * 16 + c;
    float linv = 1.0f / lL;
    #pragma unroll
    for (int dt = 0; dt < 4; dt++) {
      bf16x4 o;
      #pragma unroll
      for (int r = 0; r < 4; r++) o[r] = (bf16)(acc[dt][r] * linv);
      *(bf16x4*)&y[((size_t)(b * S_LEN + q) * N_HEAD + h) * HEAD_DIM + dt * 16 + quad * 4] = o;
    }
  }
}

// ---------------- GEMM2: out = y @ W_proj + b_proj, 128x64 tiles ----------------
__global__ __launch_bounds__(256, 2)
void k_gemm_proj(const bf16* __restrict__ A, const bf16* __restrict__ Bt,
                 const float* __restrict__ bias, float* __restrict__ out) {
  __shared__ bf16 As[128 * 32];
  __shared__ bf16 Bs[64 * 32];
  const int K = 1024;
  int bn = blockIdx.x, bm = blockIdx.y;
  int t = threadIdx.x;
  int wave = t >> 6, lane = t & 63, c = lane & 15, quad = lane >> 4;
  int wm = wave & 1, wn = wave >> 1;
  int ldrow = lane >> 2, ldcol = (lane & 3) * 8;

  const bf16* Ag = A + (size_t)(bm * 128) * K;
  const bf16* Bg = Bt + (size_t)(bn * 64) * K;

  f32x4 acc[4][2] = {};

  for (int k0 = 0; k0 < K; k0 += 32) {
    __syncthreads();
    #pragma unroll
    for (int q = 0; q < 2; q++) {
      int r0 = (wave * 2 + q) * 16;
      gl_lds16(&Ag[(size_t)(r0 + ldrow) * K + k0 + ldcol], &As[r0 * 32]);
    }
    gl_lds16(&Bg[(size_t)(wave * 16 + ldrow) * K + k0 + ldcol], &Bs[wave * 16 * 32]);
    __syncthreads();
    bf16x8 af[4];
    #pragma unroll
    for (int mt = 0; mt < 4; mt++)
      af[mt] = *(const bf16x8*)&As[(wm * 64 + mt * 16 + c) * 32 + quad * 8];
    #pragma unroll
    for (int nt = 0; nt < 2; nt++) {
      bf16x8 bfr = *(const bf16x8*)&Bs[(wn * 32 + nt * 16 + c) * 32 + quad * 8];
      #pragma unroll
      for (int mt = 0; mt < 4; mt++)
        acc[mt][nt] = __builtin_amdgcn_mfma_f32_16x16x32_bf16(af[mt], bfr, acc[mt][nt], 0, 0, 0);
    }
  }

  #pragma unroll
  for (int nt = 0; nt < 2; nt++) {
    int n = bn * 64 + wn * 32 + nt * 16 + c;
    float bv = bias[n];
    #pragma unroll
    for (int mt = 0; mt < 4; mt++) {
      #pragma unroll
      for (int r = 0; r < 4; r++) {
        int m = bm * 128 + wm * 64 + mt * 16 + quad * 4 + r;
        out[(size_t)m * D_DIM + n] = acc[mt][nt][r] + bv;
      }
    }
  }
}

extern "C" void kernel_launch(void* const* d_in, const int* in_sizes, int n_in,
                              void* d_out, int out_size, void* d_ws, size_t ws_size,
                              hipStream_t stream) {
  const float* x      = (const float*)d_in[0];
  const float* W_attn = (const float*)d_in[1];
  const float* b_attn = (const float*)d_in[2];
  const float* W_proj = (const float*)d_in[3];
  const float* b_proj = (const float*)d_in[4];
  float* out = (float*)d_out;

  bf16* x_bf = (bf16*)d_ws;
  bf16* wat  = x_bf + 4096 * 1024;
  bf16* wpt  = wat + 3072 * 1024;
  bf16* qk   = wpt + 1024 * 1024;
  bf16* vT   = qk + 8 * 1024 * 1024;
  bf16* y_bf = vT + 4 * 1024 * 1024;

  k_cast<<<4096, 256, 0, stream>>>(x, x_bf, 4096 * 1024);
  k_transpose<<<dim3(3072 / 32, 1024 / 32), 256, 0, stream>>>(W_attn, wat, 1024, 3072);
  k_transpose<<<dim3(1024 / 32, 1024 / 32), 256, 0, stream>>>(W_proj, wpt, 1024, 1024);
  k_gemm_qkv<<<dim3(24, 32), 256, 0, stream>>>(x_bf, wat, b_attn, qk, vT);
  k_attn<<<512, 512, 0, stream>>>(qk, vT, y_bf);
  k_gemm_proj<<<dim3(16, 32), 256, 0, stream>>>(y_bf, wpt, b_proj, out);
}

// Round 5
// 175.497 us; speedup vs baseline: 1.0491x; 1.0491x over previous
//
#include <hip/hip_runtime.h>

typedef __bf16 bf16;
typedef __bf16 bf16x4 __attribute__((ext_vector_type(4)));
typedef __bf16 bf16x8 __attribute__((ext_vector_type(8)));
typedef float f32x4 __attribute__((ext_vector_type(4)));

#define S_LEN 2048
#define D_DIM 1024
#define N_HEAD 16
#define HEAD_DIM 64
#define M_TOK 4096
#define BH 32

#define EXP2F(x) __builtin_amdgcn_exp2f(x)
// 1/sqrt(64) * log2(e)
#define Q_SCALE 0.18033688f

// LDS bank swizzle: conflict-free for our b64/b128 access patterns (stride 64/128, no pad)
#define SW(r, c) ((c) ^ (((r) & 3) << 4))
// K-row bit permutation sigma: bit2->bit4, bit4->bit3, bit3->bit2 (within a 64-row block).
// Storing K row kpos at LDS row sigma(kpos) makes the QK^T output's P matrix
// lane-local for the PV MFMA B-operand (pf[ks] = {p[2ks][0..3], p[2ks+1][0..3]}).
// sigma preserves (r&3) so SW(sigma(r),c) == SW(r,c). sigma has order 3; its
// inverse SIGINV (bit4->bit2, bit3->bit4, bit2->bit3) is used to pre-permute
// the GLOBAL source row so global_load_lds can write the LDS linearly.
#define SIG(r) (((r) & 0x23) | (((r) & 0x04) << 2) | (((r) & 0x18) >> 1))
#define SIGINV(y) (((y) & 0x23) | (((y) >> 2) & 0x04) | (((y) & 0x0C) << 1))

typedef __attribute__((address_space(3))) void lds_void;
typedef const __attribute__((address_space(1))) void gbl_void;

__device__ __forceinline__ void gl_lds16(const bf16* g, bf16* l) {
  __builtin_amdgcn_global_load_lds((gbl_void*)g, (lds_void*)l, 16, 0, 0);
}

// ---------------- cast fp32 -> bf16 ----------------
__global__ __launch_bounds__(256) void k_cast(const float* __restrict__ x,
                                              bf16* __restrict__ o, int n) {
  int i = (blockIdx.x * 256 + threadIdx.x) * 4;
  if (i >= n) return;
  float4 v = *(const float4*)(x + i);
  bf16x4 w;
  w[0] = (bf16)v.x; w[1] = (bf16)v.y; w[2] = (bf16)v.z; w[3] = (bf16)v.w;
  *(bf16x4*)(o + i) = w;
}

// ---------------- transpose+cast: W[K][N] fp32 -> Wt[N][K] bf16 ----------------
__global__ __launch_bounds__(256) void k_transpose(const float* __restrict__ W,
                                                   bf16* __restrict__ Wt,
                                                   int K, int N) {
  __shared__ float tile[32][33];
  int nb = blockIdx.x, kb = blockIdx.y;
  int t = threadIdx.x;
  int r = t >> 3, c4 = (t & 7) * 4;
  float4 v = *(const float4*)&W[(kb * 32 + r) * N + nb * 32 + c4];
  tile[r][c4 + 0] = v.x; tile[r][c4 + 1] = v.y;
  tile[r][c4 + 2] = v.z; tile[r][c4 + 3] = v.w;
  __syncthreads();
  bf16x4 o;
  #pragma unroll
  for (int i = 0; i < 4; i++) o[i] = (bf16)tile[c4 + i][r];
  *(bf16x4*)&Wt[(nb * 32 + r) * K + kb * 32 + c4] = o;
}

// ---------------- GEMM1: qkv = x @ W_attn + b_attn ----------------
__global__ __launch_bounds__(256, 2)
void k_gemm_qkv(const bf16* __restrict__ A, const bf16* __restrict__ Bt,
                const float* __restrict__ bias,
                bf16* __restrict__ qk, bf16* __restrict__ vT) {
  __shared__ bf16 As[128 * 32];
  __shared__ bf16 Bs[128 * 32];
  const int K = 1024;
  int bn = blockIdx.x, bm = blockIdx.y;
  int t = threadIdx.x;
  int wave = t >> 6, lane = t & 63, c = lane & 15, quad = lane >> 4;
  int wm = wave & 1, wn = wave >> 1;
  int ldrow = lane >> 2, ldcol = (lane & 3) * 8;

  const bf16* Ag = A + (size_t)(bm * 128) * K;
  const bf16* Bg = Bt + (size_t)(bn * 128) * K;

  f32x4 acc[4][4] = {};

  for (int k0 = 0; k0 < K; k0 += 32) {
    __syncthreads();
    #pragma unroll
    for (int q = 0; q < 2; q++) {
      int r0 = (wave * 2 + q) * 16;
      gl_lds16(&Ag[(size_t)(r0 + ldrow) * K + k0 + ldcol], &As[r0 * 32]);
      gl_lds16(&Bg[(size_t)(r0 + ldrow) * K + k0 + ldcol], &Bs[r0 * 32]);
    }
    __syncthreads();
    bf16x8 af[4];
    #pragma unroll
    for (int mt = 0; mt < 4; mt++)
      af[mt] = *(const bf16x8*)&As[(wm * 64 + mt * 16 + c) * 32 + quad * 8];
    #pragma unroll
    for (int nt = 0; nt < 4; nt++) {
      bf16x8 bfr = *(const bf16x8*)&Bs[(wn * 64 + nt * 16 + c) * 32 + quad * 8];
      #pragma unroll
      for (int mt = 0; mt < 4; mt++)
        acc[mt][nt] = __builtin_amdgcn_mfma_f32_16x16x32_bf16(af[mt], bfr, acc[mt][nt], 0, 0, 0);
    }
  }

  #pragma unroll
  for (int nt = 0; nt < 4; nt++) {
    int n = bn * 128 + wn * 64 + nt * 16 + c;
    int which = n >> 10, nl = n & 1023;
    int h = nl >> 6, hd = nl & 63;
    float bv = bias[n];
    #pragma unroll
    for (int mt = 0; mt < 4; mt++) {
      int m0 = bm * 128 + wm * 64 + mt * 16 + quad * 4;
      int b = m0 >> 11, s0 = m0 & 2047;
      int bh = b * N_HEAD + h;
      if (which == 2) {
        bf16x4 o;
        #pragma unroll
        for (int r = 0; r < 4; r++) o[r] = (bf16)(acc[mt][nt][r] + bv);
        *(bf16x4*)&vT[((size_t)bh * HEAD_DIM + hd) * S_LEN + s0] = o;
      } else if (which == 0) {
        #pragma unroll
        for (int r = 0; r < 4; r++)
          qk[(bh * S_LEN + s0 + r) * HEAD_DIM + hd] = (bf16)((acc[mt][nt][r] + bv) * Q_SCALE);
      } else {
        #pragma unroll
        for (int r = 0; r < 4; r++)
          qk[BH * S_LEN * HEAD_DIM + (bh * S_LEN + s0 + r) * HEAD_DIM + hd] = (bf16)(acc[mt][nt][r] + bv);
      }
    }
  }
}

// ---------------- flash attention (causal), paired q-tiles, KVBLK=128 ----------------
// grid 512, 512 thr. Complementary pair map: i<256 -> p=i>>5 (0..7);
// i>=256 -> p=15-((i-256)>>5) (15..8). Blocks i and i+256 co-reside on a CU
// (same bh -> K/V L2 reuse) with iteration counts L(p)+L(15-p) = 25 constant.
// Waves 0-3 own q-tile p (16 q-rows each), waves 4-7 own q-tile 31-p.
// KVBLK=128: half the barriers/shuffle-reductions/staging-issues per unit work
// vs KVBLK=64. LDS 64KB (2 blocks/CU).
// Staging via global_load_lds with inverse-swizzled SOURCE addresses (linear
// LDS dest): K source row pre-permuted by SIGINV, columns pre-XOR'd by SW, so
// the LDS content equals the old swizzled-ds_write layout with zero VGPR
// round-trip and zero ds_write instructions. Loads issue right after the top
// barrier; the whole iteration covers their latency; next barrier's implicit
// vmcnt(0) drain publishes them.
// P never touches LDS (SIG trick: QK^T output is lane-local for PV B-operand).
__global__ __launch_bounds__(512, 4)
void k_attn(const bf16* __restrict__ qk, const bf16* __restrict__ vT,
            bf16* __restrict__ y) {
  __shared__ bf16 Ks[2][128][64];  // [buf][sig-permuted kpos][d] (SW cols)
  __shared__ bf16 Vs[2][64][128];  // [buf][d][kpos] (SW cols)
  int bx = blockIdx.x;
  int bh, p;
  if (bx < 256) { bh = bx & 31; p = bx >> 5; }
  else          { int j = bx - 256; bh = j & 31; p = 15 - (j >> 5); }
  int t = threadIdx.x, w = t >> 6, lane = t & 63, c = lane & 15, quad = lane >> 4;
  int strip = w >> 2, wr = w & 3;
  int myTile = strip ? (31 - p) : p;
  const bf16* Qg = qk + (size_t)bh * (S_LEN * HEAD_DIM);
  const bf16* Kg = qk + (size_t)(BH + bh) * (S_LEN * HEAD_DIM);
  const bf16* Vg = vT + (size_t)bh * (HEAD_DIM * S_LEN);
  int b = bh >> 4, h = bh & 15;

  const int NKB2 = ((31 - p) >> 1) + 1;      // 128-wide K-blocks for strip 1
  const int myLast2 = myTile >> 1;           // diagonal 128-block for this strip
  const int dmask = wr * 16 + c + ((myTile & 1) << 6);  // causal threshold (local kpos)

  // ---- staging address precompute (loop-invariant, per lane) ----
  // K: LDS rows jK = w*16 + q*8 + (lane>>3); linear dest col (lane&7)*8.
  //    source row = 64*(jK>>6) + SIGINV(jK&63); source col = SW(jK, (lane&7)*8).
  int jK0 = w * 16 + (lane >> 3);
  int jK1 = jK0 + 8;                          // same (jK&3)
  int cK  = ((lane & 7) * 8) ^ ((jK0 & 3) << 4);
  int kRow0 = ((jK0 >> 6) << 6) + SIGINV(jK0 & 63);
  int kRow1 = ((jK1 >> 6) << 6) + SIGINV(jK1 & 63);
  const bf16* kSrc0 = Kg + (size_t)kRow0 * HEAD_DIM + cK;
  const bf16* kSrc1 = Kg + (size_t)kRow1 * HEAD_DIM + cK;
  // V: LDS rows jV = w*8 + q*4 + (lane>>4); dest col (lane&15)*8.
  //    source col = kb2*128 + SW(jV, (lane&15)*8).
  int jV0 = w * 8 + (lane >> 4);
  int cV  = ((lane & 15) * 8) ^ ((jV0 & 3) << 4);
  const bf16* vSrc0 = Vg + (size_t)jV0 * S_LEN + cV;
  const bf16* vSrc1 = vSrc0 + (size_t)4 * S_LEN;

  // ---- Q fragments + prologue stage of block 0 into buf 0 ----
  gl_lds16(kSrc0, &Ks[0][w * 16][0]);
  gl_lds16(kSrc1, &Ks[0][w * 16 + 8][0]);
  gl_lds16(vSrc0, &Vs[0][w * 8][0]);
  gl_lds16(vSrc1, &Vs[0][w * 8 + 4][0]);

  bf16x8 qf[2];
  f32x4 acc[4] = {};
  float mM = -1e30f, lL = 0.f;
  {
    int qr = myTile * 64 + wr * 16 + c;
    qf[0] = *(const bf16x8*)&Qg[qr * HEAD_DIM + quad * 8];
    qf[1] = *(const bf16x8*)&Qg[qr * HEAD_DIM + 32 + quad * 8];
  }

  for (int kb2 = 0; kb2 < NKB2; kb2++) {
    __syncthreads();   // drains gl_lds -> buf[cur] ready; licenses writing buf[nxt]
    int cur = kb2 & 1, nxt = cur ^ 1;
    if (kb2 + 1 < NKB2) {            // async-stage next block (drains at next barrier)
      size_t ko = (size_t)(kb2 + 1) * (128 * HEAD_DIM);
      int    vo = (kb2 + 1) * 128;
      gl_lds16(kSrc0 + ko, &Ks[nxt][w * 16][0]);
      gl_lds16(kSrc1 + ko, &Ks[nxt][w * 16 + 8][0]);
      gl_lds16(vSrc0 + vo, &Vs[nxt][w * 8][0]);
      gl_lds16(vSrc1 + vo, &Vs[nxt][w * 8 + 4][0]);
    }

    if (kb2 <= myLast2) {
      // S^T = K Q^T: lane (c,quad) reg (kt,r) holds score for local
      // kpos = 64*(kt>>2) + 32*((kt>>1)&1) + quad*8 + 4*(kt&1) + r, q-col = c.
      f32x4 sc[8];
      __builtin_amdgcn_s_setprio(1);
      #pragma unroll
      for (int kt = 0; kt < 8; kt++) {
        int krr = kt * 16 + c;
        bf16x8 kf0 = *(const bf16x8*)&Ks[cur][krr][SW(krr, quad * 8)];
        bf16x8 kf1 = *(const bf16x8*)&Ks[cur][krr][SW(krr, 32 + quad * 8)];
        f32x4 z = {};
        z = __builtin_amdgcn_mfma_f32_16x16x32_bf16(kf0, qf[0], z, 0, 0, 0);
        z = __builtin_amdgcn_mfma_f32_16x16x32_bf16(kf1, qf[1], z, 0, 0, 0);
        sc[kt] = z;
      }
      __builtin_amdgcn_s_setprio(0);

      if (kb2 == myLast2) {          // diagonal: causal mask
        #pragma unroll
        for (int kt = 0; kt < 8; kt++) {
          int kbase = ((kt >> 2) << 6) + (((kt >> 1) & 1) << 5) + quad * 8 + ((kt & 1) << 2);
          #pragma unroll
          for (int r = 0; r < 4; r++)
            if (kbase + r > dmask) sc[kt][r] = -1e30f;
        }
      }

      // online softmax (lane's q-row = c); P stays in registers: pf[ks] holds
      // kpos = ks*32 + quad*8 + e  -> exactly the PV B-operand order.
      bf16x8 pf[4];
      {
        float tm[8];
        #pragma unroll
        for (int kt = 0; kt < 8; kt++)
          tm[kt] = fmaxf(fmaxf(sc[kt][0], sc[kt][1]), fmaxf(sc[kt][2], sc[kt][3]));
        float mx = fmaxf(fmaxf(fmaxf(tm[0], tm[1]), fmaxf(tm[2], tm[3])),
                         fmaxf(fmaxf(tm[4], tm[5]), fmaxf(tm[6], tm[7])));
        mx = fmaxf(mx, __shfl_xor(mx, 16));
        mx = fmaxf(mx, __shfl_xor(mx, 32));
        float mnew = fmaxf(mM, mx);
        float alpha = EXP2F(mM - mnew);
        mM = mnew;
        lL *= alpha;
        #pragma unroll
        for (int dt = 0; dt < 4; dt++)
          #pragma unroll
          for (int r = 0; r < 4; r++) acc[dt][r] *= alpha;
        float ss[4] = {0.f, 0.f, 0.f, 0.f};
        #pragma unroll
        for (int kt = 0; kt < 8; kt++) {
          float e0 = EXP2F(sc[kt][0] - mM), e1 = EXP2F(sc[kt][1] - mM);
          float e2 = EXP2F(sc[kt][2] - mM), e3 = EXP2F(sc[kt][3] - mM);
          pf[kt >> 1][(kt & 1) * 4 + 0] = (bf16)e0;
          pf[kt >> 1][(kt & 1) * 4 + 1] = (bf16)e1;
          pf[kt >> 1][(kt & 1) * 4 + 2] = (bf16)e2;
          pf[kt >> 1][(kt & 1) * 4 + 3] = (bf16)e3;
          ss[kt & 3] += (e0 + e1) + (e2 + e3);
        }
        float sum = (ss[0] + ss[1]) + (ss[2] + ss[3]);
        sum += __shfl_xor(sum, 16);
        sum += __shfl_xor(sum, 32);
        lL += sum;
      }

      // O^T += V^T P^T
      __builtin_amdgcn_s_setprio(1);
      #pragma unroll
      for (int ks = 0; ks < 4; ks++) {
        #pragma unroll
        for (int dt = 0; dt < 4; dt++) {
          int vrow = dt * 16 + c;
          bf16x8 vf = *(const bf16x8*)&Vs[cur][vrow][SW(vrow, ks * 32 + quad * 8)];
          acc[dt] = __builtin_amdgcn_mfma_f32_16x16x32_bf16(vf, pf[ks], acc[dt], 0, 0, 0);
        }
      }
      __builtin_amdgcn_s_setprio(0);
    }
  }

  {
    int q = myTile * 64 + wr * 16 + c;
    float linv = 1.0f / lL;
    #pragma unroll
    for (int dt = 0; dt < 4; dt++) {
      bf16x4 o;
      #pragma unroll
      for (int r = 0; r < 4; r++) o[r] = (bf16)(acc[dt][r] * linv);
      *(bf16x4*)&y[((size_t)(b * S_LEN + q) * N_HEAD + h) * HEAD_DIM + dt * 16 + quad * 4] = o;
    }
  }
}

// ---------------- GEMM2: out = y @ W_proj + b_proj, 128x64 tiles ----------------
__global__ __launch_bounds__(256, 2)
void k_gemm_proj(const bf16* __restrict__ A, const bf16* __restrict__ Bt,
                 const float* __restrict__ bias, float* __restrict__ out) {
  __shared__ bf16 As[128 * 32];
  __shared__ bf16 Bs[64 * 32];
  const int K = 1024;
  int bn = blockIdx.x, bm = blockIdx.y;
  int t = threadIdx.x;
  int wave = t >> 6, lane = t & 63, c = lane & 15, quad = lane >> 4;
  int wm = wave & 1, wn = wave >> 1;
  int ldrow = lane >> 2, ldcol = (lane & 3) * 8;

  const bf16* Ag = A + (size_t)(bm * 128) * K;
  const bf16* Bg = Bt + (size_t)(bn * 64) * K;

  f32x4 acc[4][2] = {};

  for (int k0 = 0; k0 < K; k0 += 32) {
    __syncthreads();
    #pragma unroll
    for (int q = 0; q < 2; q++) {
      int r0 = (wave * 2 + q) * 16;
      gl_lds16(&Ag[(size_t)(r0 + ldrow) * K + k0 + ldcol], &As[r0 * 32]);
    }
    gl_lds16(&Bg[(size_t)(wave * 16 + ldrow) * K + k0 + ldcol], &Bs[wave * 16 * 32]);
    __syncthreads();
    bf16x8 af[4];
    #pragma unroll
    for (int mt = 0; mt < 4; mt++)
      af[mt] = *(const bf16x8*)&As[(wm * 64 + mt * 16 + c) * 32 + quad * 8];
    #pragma unroll
    for (int nt = 0; nt < 2; nt++) {
      bf16x8 bfr = *(const bf16x8*)&Bs[(wn * 32 + nt * 16 + c) * 32 + quad * 8];
      #pragma unroll
      for (int mt = 0; mt < 4; mt++)
        acc[mt][nt] = __builtin_amdgcn_mfma_f32_16x16x32_bf16(af[mt], bfr, acc[mt][nt], 0, 0, 0);
    }
  }

  #pragma unroll
  for (int nt = 0; nt < 2; nt++) {
    int n = bn * 64 + wn * 32 + nt * 16 + c;
    float bv = bias[n];
    #pragma unroll
    for (int mt = 0; mt < 4; mt++) {
      #pragma unroll
      for (int r = 0; r < 4; r++) {
        int m = bm * 128 + wm * 64 + mt * 16 + quad * 4 + r;
        out[(size_t)m * D_DIM + n] = acc[mt][nt][r] + bv;
      }
    }
  }
}

extern "C" void kernel_launch(void* const* d_in, const int* in_sizes, int n_in,
                              void* d_out, int out_size, void* d_ws, size_t ws_size,
                              hipStream_t stream) {
  const float* x      = (const float*)d_in[0];
  const float* W_attn = (const float*)d_in[1];
  const float* b_attn = (const float*)d_in[2];
  const float* W_proj = (const float*)d_in[3];
  const float* b_proj = (const float*)d_in[4];
  float* out = (float*)d_out;

  bf16* x_bf = (bf16*)d_ws;
  bf16* wat  = x_bf + 4096 * 1024;
  bf16* wpt  = wat + 3072 * 1024;
  bf16* qk   = wpt + 1024 * 1024;
  bf16* vT   = qk + 8 * 1024 * 1024;
  bf16* y_bf = vT + 4 * 1024 * 1024;

  k_cast<<<4096, 256, 0, stream>>>(x, x_bf, 4096 * 1024);
  k_transpose<<<dim3(3072 / 32, 1024 / 32), 256, 0, stream>>>(W_attn, wat, 1024, 3072);
  k_transpose<<<dim3(1024 / 32, 1024 / 32), 256, 0, stream>>>(W_proj, wpt, 1024, 1024);
  k_gemm_qkv<<<dim3(24, 32), 256, 0, stream>>>(x_bf, wat, b_attn, qk, vT);
  k_attn<<<512, 512, 0, stream>>>(qk, vT, y_bf);
  k_gemm_proj<<<dim3(16, 32), 256, 0, stream>>>(y_bf, wpt, b_proj, out);
}